// Round 11
// baseline (3404.236 us; speedup 1.0000x reference)
//
#include <hip/hip_runtime.h>
#include <math.h>

#define BATCH 64
#define SEQ 512
#define DIM 1024
#define HID 1024
#define KBANDS 4
#define DT_C 0.05f
#define CNT_STRIDE 32   // one counter per 128B line

// ---------------- alpha: softmax tau mixer -> alpha[b] ----------------
__global__ void alpha_kernel(const float* __restrict__ complexity,
                             const float* __restrict__ tau_bands,
                             const float* __restrict__ mixer_w,
                             const float* __restrict__ mixer_b,
                             float* __restrict__ alpha) {
    int b = threadIdx.x;
    if (b < BATCH) {
        float c = complexity[b];
        float lg[KBANDS];
        float mx = -1e30f;
        #pragma unroll
        for (int k = 0; k < KBANDS; k++) {
            lg[k] = c * mixer_w[k] + mixer_b[k];
            mx = fmaxf(mx, lg[k]);
        }
        float se = 0.f, tau = 0.f;
        #pragma unroll
        for (int k = 0; k < KBANDS; k++) {
            float e = expf(lg[k] - mx);
            se += e;
            tau += tau_bands[k] * e;
        }
        tau /= se;
        alpha[b] = expf(-DT_C / tau);
    }
}

// ------------- xw = x @ W_in^T + bias, written into d_out's output region -------------
#define BM 64
#define BN 64
#define BK 16
__global__ __launch_bounds__(256) void in_gemm(const float* __restrict__ x,
                                               const float* __restrict__ Win,
                                               const float* __restrict__ bias,
                                               float* __restrict__ out) {
    __shared__ float As[BK][BM + 4];
    __shared__ float Bs[BK][BN + 4];
    int tid = threadIdx.x;
    int tx = tid & 15, ty = tid >> 4;
    int m0 = blockIdx.x * BM;
    int n0 = blockIdx.y * BN;
    float c[4][4] = {};
    int lmm = tid >> 2;
    int lkq = (tid & 3) * 4;
    for (int k0 = 0; k0 < 1024; k0 += BK) {
        float4 a4 = *(const float4*)(x + (size_t)(m0 + lmm) * 1024 + k0 + lkq);
        float4 b4 = *(const float4*)(Win + (size_t)(n0 + lmm) * 1024 + k0 + lkq);
        As[lkq + 0][lmm] = a4.x; As[lkq + 1][lmm] = a4.y;
        As[lkq + 2][lmm] = a4.z; As[lkq + 3][lmm] = a4.w;
        Bs[lkq + 0][lmm] = b4.x; Bs[lkq + 1][lmm] = b4.y;
        Bs[lkq + 2][lmm] = b4.z; Bs[lkq + 3][lmm] = b4.w;
        __syncthreads();
        #pragma unroll
        for (int kk = 0; kk < BK; kk++) {
            float a[4], bb[4];
            #pragma unroll
            for (int i = 0; i < 4; i++) a[i] = As[kk][ty * 4 + i];
            #pragma unroll
            for (int j = 0; j < 4; j++) bb[j] = Bs[kk][tx * 4 + j];
            #pragma unroll
            for (int i = 0; i < 4; i++)
                #pragma unroll
                for (int j = 0; j < 4; j++)
                    c[i][j] += a[i] * bb[j];
        }
        __syncthreads();
    }
    int n = n0 + tx * 4;
    float4 bias4 = *(const float4*)(bias + n);
    #pragma unroll
    for (int i = 0; i < 4; i++) {
        int m = m0 + ty * 4 + i;
        float4 st;
        st.x = c[i][0] + bias4.x;
        st.y = c[i][1] + bias4.y;
        st.z = c[i][2] + bias4.z;
        st.w = c[i][3] + bias4.w;
        *(float4*)(out + (size_t)m * 1024 + n) = st;
    }
}

// ------------- cooperative recurrence (R5 datapath, per-group gate) ---------
// 256 blocks = 4 b-slices x 64 j-slices; 4 waves/block. Wave w consumes
// k-quarter [256w,256w+256), produced by group g=w = blocks js' in
// [16w,16w+16). DATAPATH = R5 (proven 1.87ms): bf16 hi/lo parity planes in
// hbuf; producer splits own value, 2 sc1 short stores; consumer sc1 dwordx4
// staging -> plain-pitch LDS -> bf16x8 frags -> 24 MFMA; W register-resident.
// DEEP-BUFFER (R8/R10) REVERTED: plain-cacheable staging measured -10%.
// SYNC (this round): per-(t,bs,GROUP) counters (target 16; same fetch_add/
// poll mechanism as R5, 4x counters). Wave w's lane0 spins on group w's
// counter only -> gate fan-in 64->16 and groups overlap. Staging is
// k-partitioned so wave w stages exactly what it MFMAs -> stage barrier
// GONE (lgkmcnt orders LDS write->read within the wave). Coalescing kept:
// lane=16B contig, 32 lanes=512B contig per row (R6's 128B-stride mistake
// avoided). 2 barriers/step (red, drain).
// Parity invariant: all 4 waves pass gates before red barrier => before any
// h[t] store, all 64 blocks finished step t-1 => slot (t&1) fully consumed.

#define HPITCH 2064               // bytes per LDS plane row (1024*2 + 16 pad)
#define LDS_HI  0
#define LDS_LO  33024             // 16*HPITCH
#define LDS_RED 66048             // 4KB reduction buffer
#define LDS_TOTAL 70144
#define HB_PLANE 131072           // bytes per hi (or lo) plane [64][1024] ushort
#define HB_SLOT  262144           // hi+lo planes per parity slot

typedef short bf16x8 __attribute__((ext_vector_type(8)));
typedef float f32x4 __attribute__((ext_vector_type(4)));

__device__ __forceinline__ unsigned bf16rn(float x) {
    unsigned u = __float_as_uint(x);
    return (u + 0x7fffu + ((u >> 16) & 1u)) >> 16;
}

__device__ __forceinline__ void splitf(float f, unsigned short* hi, unsigned short* lo) {
    unsigned h = bf16rn(f);
    float r = f - __uint_as_float(h << 16);
    *hi = (unsigned short)h;
    *lo = (unsigned short)bf16rn(r);
}

__global__ __launch_bounds__(256, 1) void recur_coop(const float* __restrict__ Wrec,
                                                     const float* __restrict__ alpha,
                                                     float* __restrict__ out,
                                                     int* __restrict__ cnt,
                                                     unsigned short* __restrict__ hbuf) {
    extern __shared__ char lbase[];

    int tid  = threadIdx.x;
    int bs   = blockIdx.x & 3;        // b-slice 0..3
    int js   = blockIdx.x >> 2;       // j-slice 0..63
    int lane = tid & 63;
    int w    = tid >> 6;              // wave 0..3 = k-quarter owner
    int row  = lane & 15;             // frag row: batch (A) / j (B)
    int kq   = lane >> 4;             // k-subchunk within 32-wide MFMA window
    int gself = js >> 4;              // group this block produces into

    // ---- W fragments (B operand), converted ONCE into registers ----------
    bf16x8 wh[8], wl[8];
    {
        const float* wsrc = Wrec + (size_t)(js * 16 + row) * HID + w * 256 + kq * 8;
        #pragma unroll
        for (int ks = 0; ks < 8; ks++) {
            float4 f0 = *(const float4*)(wsrc + ks * 32);
            float4 f1 = *(const float4*)(wsrc + ks * 32 + 4);
            union { unsigned short u[8]; bf16x8 v; } H, L;
            splitf(f0.x, &H.u[0], &L.u[0]);
            splitf(f0.y, &H.u[1], &L.u[1]);
            splitf(f0.z, &H.u[2], &L.u[2]);
            splitf(f0.w, &H.u[3], &L.u[3]);
            splitf(f1.x, &H.u[4], &L.u[4]);
            splitf(f1.y, &H.u[5], &L.u[5]);
            splitf(f1.z, &H.u[6], &L.u[6]);
            splitf(f1.w, &H.u[7], &L.u[7]);
            wh[ks] = H.v;
            wl[ks] = L.v;
        }
    }

    // epilogue mapping: thread owns (batch bs*16 + eb, hidden j js*16 + ej)
    int eb = tid >> 4;
    int ej = tid & 15;
    int bglob = bs * 16 + eb;
    int jglob = js * 16 + ej;
    float a_reg = alpha[bglob];
    float om = 1.f - a_reg;
    float* xwp = out + (size_t)bglob * SEQ * HID + jglob;

    // wave-private k-partitioned staging: lane covers rows {sr2, sr2+2, ...},
    // 16B chunk sc32 of its wave's 512B quarter-row. 32 lanes = 512B contig.
    int sr2  = lane >> 5;             // 0/1: row parity within pair
    int sc32 = lane & 31;             // 16B chunk in 512B
    const char* hb_w = (const char*)hbuf + (size_t)(bs * 16 + sr2) * 2048
                                   + w * 512 + sc32 * 16;
    char* ph_base = (char*)hbuf + (size_t)bglob * 2048 + jglob * 2;

    char* dh_w = lbase + LDS_HI + sr2 * HPITCH + w * 512 + sc32 * 16;
    char* dl_w = lbase + LDS_LO + sr2 * HPITCH + w * 512 + sc32 * 16;
    const char* ah_base = lbase + LDS_HI + row * HPITCH + (w * 256 + kq * 8) * 2;
    const char* al_base = lbase + LDS_LO + row * HPITCH + (w * 256 + kq * 8) * 2;
    float* redp = (float*)(lbase + LDS_RED);

    float hp = 0.f;

    for (int t = 0; t < SEQ; t++) {
        float xw = *xwp;              // independent of h[t-1]; issue early
        float sum = 0.f;
        if (t > 0) {
            // ---- per-wave gate: only OUR group's 16 producers --------------
            if (lane == 0) {
                int* cp = cnt + (size_t)((t - 1) * 16 + bs * 4 + w) * CNT_STRIDE;
                int spins = 0;
                while (__hip_atomic_load(cp, __ATOMIC_RELAXED,
                                         __HIP_MEMORY_SCOPE_AGENT) < 16) {
                    __builtin_amdgcn_s_sleep(1);
                    if (++spins >= 8192) {      // insurance re-check via RMW
                        spins = 0;
                        if (__hip_atomic_fetch_add(cp, 0, __ATOMIC_RELAXED,
                                __HIP_MEMORY_SCOPE_AGENT) >= 16) break;
                    }
                }
            }
            // wave reconvergence = broadcast within the wave (lockstep)
            // ---- wave-private stage of own k-quarter (sc1 loads) -----------
            {
                const char* bh = hb_w + (size_t)((t - 1) & 1) * HB_SLOT;
                const char* bl = bh + HB_PLANE;
                float4 v[16];
                #pragma unroll
                for (int it = 0; it < 8; it++) {
                    const char* p = bh + it * 4096;   // 2 rows per iter
                    asm volatile("global_load_dwordx4 %0, %1, off sc0 sc1"
                                 : "=v"(v[it]) : "v"(p) : "memory");
                }
                #pragma unroll
                for (int it = 0; it < 8; it++) {
                    const char* p = bl + it * 4096;
                    asm volatile("global_load_dwordx4 %0, %1, off sc0 sc1"
                                 : "=v"(v[8 + it]) : "v"(p) : "memory");
                }
                asm volatile("s_waitcnt vmcnt(0)" ::: "memory");
                #pragma unroll
                for (int it = 0; it < 8; it++)
                    *(float4*)(dh_w + it * (2 * HPITCH)) = v[it];
                #pragma unroll
                for (int it = 0; it < 8; it++)
                    *(float4*)(dl_w + it * (2 * HPITCH)) = v[8 + it];
            }
            // no stage barrier: wave w staged exactly what wave w reads;
            // compiler orders LDS write->read with lgkmcnt
            // ---- MFMA over own k-quarter: 8 k-steps x 3 split products -----
            f32x4 acc0 = {0.f, 0.f, 0.f, 0.f};
            f32x4 acc1 = {0.f, 0.f, 0.f, 0.f};
            #pragma unroll
            for (int ks = 0; ks < 8; ks++) {
                bf16x8 ah = *(const bf16x8*)(ah_base + ks * 64);
                bf16x8 al = *(const bf16x8*)(al_base + ks * 64);
                if (ks & 1) {
                    acc1 = __builtin_amdgcn_mfma_f32_16x16x32_bf16(ah, wh[ks], acc1, 0, 0, 0);
                    acc1 = __builtin_amdgcn_mfma_f32_16x16x32_bf16(al, wh[ks], acc1, 0, 0, 0);
                    acc1 = __builtin_amdgcn_mfma_f32_16x16x32_bf16(ah, wl[ks], acc1, 0, 0, 0);
                } else {
                    acc0 = __builtin_amdgcn_mfma_f32_16x16x32_bf16(ah, wh[ks], acc0, 0, 0, 0);
                    acc0 = __builtin_amdgcn_mfma_f32_16x16x32_bf16(al, wh[ks], acc0, 0, 0, 0);
                    acc0 = __builtin_amdgcn_mfma_f32_16x16x32_bf16(ah, wl[ks], acc0, 0, 0, 0);
                }
            }
            // ---- cross-wave k reduction ------------------------------------
            #pragma unroll
            for (int r = 0; r < 4; r++)
                redp[w * 256 + (kq * 4 + r) * 16 + row] = acc0[r] + acc1[r];
            __syncthreads();          // barrier 1: red ready (joins all gates)
            sum = redp[tid] + redp[256 + tid] + redp[512 + tid] + redp[768 + tid];
        }
        float pre = sum + xw;
        float hn = a_reg * hp + om * tanhf(pre);
        *xwp = hn;                    // plain store: output only, block-local
        if (t == SEQ - 1)
            out[(size_t)BATCH * SEQ * HID + (size_t)bglob * HID + jglob] = hn;
        // producer-side split of OWN value; sc1 stores into slot (t & 1)
        {
            unsigned short hi16, lo16;
            splitf(hn, &hi16, &lo16);
            unsigned hv = hi16, lv = lo16;
            char* ph = ph_base + (size_t)(t & 1) * HB_SLOT;
            char* pl = ph + HB_PLANE;
            asm volatile("global_store_short %0, %1, off sc0 sc1"
                         :: "v"(ph), "v"(hv) : "memory");
            asm volatile("global_store_short %0, %1, off sc0 sc1"
                         :: "v"(pl), "v"(lv) : "memory");
        }
        asm volatile("s_waitcnt vmcnt(0)" ::: "memory");  // drain own stores
        __syncthreads();              // barrier 2: ALL threads' stores drained
        if (tid == 0)
            __hip_atomic_fetch_add(
                cnt + (size_t)(t * 16 + bs * 4 + gself) * CNT_STRIDE, 1,
                __ATOMIC_RELAXED, __HIP_MEMORY_SCOPE_AGENT);
        hp = hn;
        xwp += HID;
    }
}

extern "C" void kernel_launch(void* const* d_in, const int* in_sizes, int n_in,
                              void* d_out, int out_size, void* d_ws, size_t ws_size,
                              hipStream_t stream) {
    const float* x          = (const float*)d_in[0];
    const float* complexity = (const float*)d_in[1];
    const float* Wrec       = (const float*)d_in[2];
    const float* Win        = (const float*)d_in[3];
    const float* bias       = (const float*)d_in[4];
    const float* tau_bands  = (const float*)d_in[5];
    const float* mixer_w    = (const float*)d_in[6];
    const float* mixer_b    = (const float*)d_in[7];
    float* out = (float*)d_out;

    float* alpha = (float*)d_ws;                               // 256 B
    int*   cnt   = (int*)((char*)d_ws + 256);                  // SEQ*16 counters, 1MB
    unsigned short* hbuf = (unsigned short*)((char*)d_ws + 256 + 1048576);

    hipMemsetAsync(cnt, 0, SEQ * 16 * CNT_STRIDE * sizeof(int), stream);
    alpha_kernel<<<1, 64, 0, stream>>>(complexity, tau_bands, mixer_w, mixer_b, alpha);
    in_gemm<<<dim3(32768 / BM, 1024 / BN), 256, 0, stream>>>(x, Win, bias, out);

    hipFuncSetAttribute((const void*)recur_coop,
                        hipFuncAttributeMaxDynamicSharedMemorySize, LDS_TOTAL);
    void* args[] = { (void*)&Wrec, (void*)&alpha, (void*)&out, (void*)&cnt, (void*)&hbuf };
    hipLaunchCooperativeKernel((void*)recur_coop, dim3(256), dim3(256),
                               args, LDS_TOTAL, stream);
}

// Round 12
// 2544.178 us; speedup vs baseline: 1.3380x; 1.3380x over previous
//
#include <hip/hip_runtime.h>
#include <math.h>

#define BATCH 64
#define SEQ 512
#define DIM 1024
#define HID 1024
#define KBANDS 4
#define DT_C 0.05f
#define CNT_STRIDE 32   // one counter per 128B line

typedef short bf16x8 __attribute__((ext_vector_type(8)));
typedef float f32x4 __attribute__((ext_vector_type(4)));

__device__ __forceinline__ unsigned bf16rn(float x) {
    unsigned u = __float_as_uint(x);
    return (u + 0x7fffu + ((u >> 16) & 1u)) >> 16;
}

__device__ __forceinline__ void splitf(float f, unsigned short* hi, unsigned short* lo) {
    unsigned h = bf16rn(f);
    float r = f - __uint_as_float(h << 16);
    *hi = (unsigned short)h;
    *lo = (unsigned short)bf16rn(r);
}

__device__ __forceinline__ void split_bf16(float4 f, ushort4* hi, ushort4* lo) {
    unsigned short h0, h1, h2, h3, l0, l1, l2, l3;
    splitf(f.x, &h0, &l0); splitf(f.y, &h1, &l1);
    splitf(f.z, &h2, &l2); splitf(f.w, &h3, &l3);
    *hi = make_ushort4(h0, h1, h2, h3);
    *lo = make_ushort4(l0, l1, l2, l3);
}

// ---------------- alpha: softmax tau mixer -> alpha[b] ----------------
__global__ void alpha_kernel(const float* __restrict__ complexity,
                             const float* __restrict__ tau_bands,
                             const float* __restrict__ mixer_w,
                             const float* __restrict__ mixer_b,
                             float* __restrict__ alpha) {
    int b = threadIdx.x;
    if (b < BATCH) {
        float c = complexity[b];
        float lg[KBANDS];
        float mx = -1e30f;
        #pragma unroll
        for (int k = 0; k < KBANDS; k++) {
            lg[k] = c * mixer_w[k] + mixer_b[k];
            mx = fmaxf(mx, lg[k]);
        }
        float se = 0.f, tau = 0.f;
        #pragma unroll
        for (int k = 0; k < KBANDS; k++) {
            float e = expf(lg[k] - mx);
            se += e;
            tau += tau_bands[k] * e;
        }
        tau /= se;
        alpha[b] = expf(-DT_C / tau);
    }
}

// ---------------- W_in -> bf16 hi/lo planes (once) --------------------
__global__ __launch_bounds__(256) void win_split(const float* __restrict__ win,
                                                 unsigned short* __restrict__ whi,
                                                 unsigned short* __restrict__ wlo) {
    size_t i = ((size_t)blockIdx.x * 256 + threadIdx.x) * 4;
    float4 f = *(const float4*)(win + i);
    ushort4 h4, l4;
    split_bf16(f, &h4, &l4);
    *(ushort4*)(whi + i) = h4;
    *(ushort4*)(wlo + i) = l4;
}

// ------------- xw = x @ W_in^T + bias via bf16x3 MFMA -----------------
// 64M x 64N per block, BK=128 LDS rounds. Wave w owns N-sub [16w,16w+16).
// A (x) split on the fly; B (Win) preconverted hi/lo planes.
// D mapping (verified, R5): m = (lane>>4)*4 + r, n = lane&15.
// LDS rows padded to 272B: frag reads 2-way bank alias (free, m136).
#define RP 272                       // bytes per LDS row (128 bf16 + 8 pad)
#define IG_LDS (4 * 64 * RP)         // Ahi, Alo, Bhi, Blo = 69632 B

__global__ __launch_bounds__(256) void in_gemm_mfma(const float* __restrict__ x,
                                                    const unsigned short* __restrict__ whi,
                                                    const unsigned short* __restrict__ wlo,
                                                    const float* __restrict__ bias,
                                                    float* __restrict__ out) {
    extern __shared__ char lg[];
    char* Ahi = lg;
    char* Alo = lg + 64 * RP;
    char* Bhi = lg + 2 * 64 * RP;
    char* Blo = lg + 3 * 64 * RP;

    int tid  = threadIdx.x;
    int m0   = blockIdx.x * 64;
    int n0   = blockIdx.y * 64;
    int lane = tid & 63;
    int w    = tid >> 6;
    int row  = lane & 15;
    int kq   = lane >> 4;

    int srow = tid >> 2;             // staging row 0..63
    int skeg = (tid & 3) * 32;       // element offset within 128-k chunk

    const float* xsrc = x + (size_t)(m0 + srow) * 1024 + skeg;
    const unsigned short* bhsrc = whi + (size_t)(n0 + srow) * 1024 + skeg;
    const unsigned short* blsrc = wlo + (size_t)(n0 + srow) * 1024 + skeg;
    char* dah = Ahi + srow * RP + skeg * 2;
    char* dal = Alo + srow * RP + skeg * 2;
    char* dbh = Bhi + srow * RP + skeg * 2;
    char* dbl = Blo + srow * RP + skeg * 2;

    f32x4 acc[4];
    #pragma unroll
    for (int mt = 0; mt < 4; mt++) acc[mt] = (f32x4){0.f, 0.f, 0.f, 0.f};

    for (int k0 = 0; k0 < 1024; k0 += 128) {
        // ---- stage A (split fp32 -> hi/lo) and B (copy preconverted) ----
        #pragma unroll
        for (int i = 0; i < 8; i++) {
            float4 f = *(const float4*)(xsrc + k0 + i * 4);
            ushort4 h4, l4;
            split_bf16(f, &h4, &l4);
            *(ushort4*)(dah + i * 8) = h4;
            *(ushort4*)(dal + i * 8) = l4;
        }
        #pragma unroll
        for (int i = 0; i < 4; i++) {
            *(float4*)(dbh + i * 16) = *(const float4*)(bhsrc + k0 + i * 8);
            *(float4*)(dbl + i * 16) = *(const float4*)(blsrc + k0 + i * 8);
        }
        __syncthreads();
        // ---- MFMA: 4 k-steps x 4 m-tiles x 3 split products -------------
        #pragma unroll
        for (int ks = 0; ks < 4; ks++) {
            int koff = (ks * 32 + kq * 8) * 2;
            bf16x8 bh = *(const bf16x8*)(Bhi + (w * 16 + row) * RP + koff);
            bf16x8 bl = *(const bf16x8*)(Blo + (w * 16 + row) * RP + koff);
            #pragma unroll
            for (int mt = 0; mt < 4; mt++) {
                bf16x8 ah = *(const bf16x8*)(Ahi + (mt * 16 + row) * RP + koff);
                bf16x8 al = *(const bf16x8*)(Alo + (mt * 16 + row) * RP + koff);
                acc[mt] = __builtin_amdgcn_mfma_f32_16x16x32_bf16(ah, bh, acc[mt], 0, 0, 0);
                acc[mt] = __builtin_amdgcn_mfma_f32_16x16x32_bf16(al, bh, acc[mt], 0, 0, 0);
                acc[mt] = __builtin_amdgcn_mfma_f32_16x16x32_bf16(ah, bl, acc[mt], 0, 0, 0);
            }
        }
        __syncthreads();
    }
    // ---- epilogue: D(m = kq*4+r, n = lane&15) + bias --------------------
    int n = n0 + w * 16 + (lane & 15);
    float bn = bias[n];
    #pragma unroll
    for (int mt = 0; mt < 4; mt++)
        #pragma unroll
        for (int r = 0; r < 4; r++)
            out[(size_t)(m0 + mt * 16 + kq * 4 + r) * 1024 + n] = acc[mt][r] + bn;
}

// ------------- cooperative recurrence (EXACT R5, proven 1.87ms) -------------
// 256 blocks = 4 b-slices x 64 j-slices; 4 waves/block.
// bf16 hi/lo PARITY planes in hbuf; producer splits own value, 2 sc1 short
// stores; consumer sc1 dwordx4 staging -> plain-pitch LDS -> bf16x8 frags ->
// 24 MFMA; W frags register-resident. Sync: per-(t,bs) 128B-strided counters;
// tid0 relaxed poll <64 -> syncthreads; epilogue: stores -> vmcnt(0) ->
// syncthreads -> tid0 fetch_add(+1).
// R7 (flag-store sync), R10 (deep cacheable buffer), R11 (per-group gate)
// all measured WORSE -- do not revisit.

#define HPITCH 2064               // bytes per LDS plane row (1024*2 + 16 pad)
#define LDS_HI  0
#define LDS_LO  33024             // 16*HPITCH
#define LDS_RED 66048             // 4KB reduction buffer
#define LDS_TOTAL 70144
#define HB_PLANE 131072           // bytes per hi (or lo) plane [64][1024] ushort
#define HB_SLOT  262144           // hi+lo planes per parity slot

__global__ __launch_bounds__(256, 1) void recur_coop(const float* __restrict__ Wrec,
                                                     const float* __restrict__ alpha,
                                                     float* __restrict__ out,
                                                     int* __restrict__ cnt,
                                                     unsigned short* __restrict__ hbuf) {
    extern __shared__ char lbase[];

    int tid  = threadIdx.x;
    int bs   = blockIdx.x & 3;        // b-slice 0..3
    int js   = blockIdx.x >> 2;       // j-slice 0..63
    int lane = tid & 63;
    int w    = tid >> 6;              // wave 0..3 = k-quarter owner
    int row  = lane & 15;             // frag row: batch (A) / j (B)
    int kq   = lane >> 4;             // k-subchunk within 32-wide MFMA window

    // ---- W fragments (B operand), converted ONCE into registers ----------
    bf16x8 wh[8], wl[8];
    {
        const float* wsrc = Wrec + (size_t)(js * 16 + row) * HID + w * 256 + kq * 8;
        #pragma unroll
        for (int ks = 0; ks < 8; ks++) {
            float4 f0 = *(const float4*)(wsrc + ks * 32);
            float4 f1 = *(const float4*)(wsrc + ks * 32 + 4);
            union { unsigned short u[8]; bf16x8 v; } H, L;
            splitf(f0.x, &H.u[0], &L.u[0]);
            splitf(f0.y, &H.u[1], &L.u[1]);
            splitf(f0.z, &H.u[2], &L.u[2]);
            splitf(f0.w, &H.u[3], &L.u[3]);
            splitf(f1.x, &H.u[4], &L.u[4]);
            splitf(f1.y, &H.u[5], &L.u[5]);
            splitf(f1.z, &H.u[6], &L.u[6]);
            splitf(f1.w, &H.u[7], &L.u[7]);
            wh[ks] = H.v;
            wl[ks] = L.v;
        }
    }

    // epilogue mapping: thread owns (batch bs*16 + eb, hidden j js*16 + ej)
    int eb = tid >> 4;
    int ej = tid & 15;
    int bglob = bs * 16 + eb;
    int jglob = js * 16 + ej;
    float a_reg = alpha[bglob];
    float om = 1.f - a_reg;
    float* xwp = out + (size_t)bglob * SEQ * HID + jglob;

    // staging mapping (R5): srow = batch row 0..15, sl16 = k-chunk lane
    int srow = tid >> 4, sl16 = tid & 15;
    const char* hb_lane = (const char*)hbuf + (size_t)(bs * 16 + srow) * 2048 + sl16 * 16;
    char* ph_base = (char*)hbuf + (size_t)bglob * 2048 + jglob * 2;

    float hp = 0.f;
    float* redp = (float*)(lbase + LDS_RED);
    const char* ah_base = lbase + LDS_HI + row * HPITCH + (w * 256 + kq * 8) * 2;
    const char* al_base = lbase + LDS_LO + row * HPITCH + (w * 256 + kq * 8) * 2;
    char* dh = lbase + LDS_HI + srow * HPITCH + sl16 * 16;
    char* dl = lbase + LDS_LO + srow * HPITCH + sl16 * 16;

    for (int t = 0; t < SEQ; t++) {
        float xw = *xwp;              // independent of h[t-1]; issue early
        float sum = 0.f;
        if (t > 0) {
            if (tid == 0) {
                int* cp = cnt + (size_t)((t - 1) * 4 + bs) * CNT_STRIDE;
                int spins = 0;
                while (__hip_atomic_load(cp, __ATOMIC_RELAXED,
                                         __HIP_MEMORY_SCOPE_AGENT) < 64) {
                    __builtin_amdgcn_s_sleep(1);
                    if (++spins >= 8192) {      // insurance re-check via RMW
                        spins = 0;
                        if (__hip_atomic_fetch_add(cp, 0, __ATOMIC_RELAXED,
                                __HIP_MEMORY_SCOPE_AGENT) >= 64) break;
                    }
                }
            }
            __syncthreads();          // broadcast: h[t-1] slot globally visible
            // ---- stage bf16 hi/lo planes of h[t-1] (sc1 loads) ------------
            {
                const char* bh = hb_lane + (size_t)((t - 1) & 1) * HB_SLOT;
                const char* bl = bh + HB_PLANE;
                float4 v[16];
                #pragma unroll
                for (int it = 0; it < 8; it++)
                    asm volatile("global_load_dwordx4 %0, %1, off offset:%2 sc0 sc1"
                                 : "=v"(v[it]) : "v"(bh), "i"(it * 256) : "memory");
                #pragma unroll
                for (int it = 0; it < 8; it++)
                    asm volatile("global_load_dwordx4 %0, %1, off offset:%2 sc0 sc1"
                                 : "=v"(v[8 + it]) : "v"(bl), "i"(it * 256) : "memory");
                asm volatile("s_waitcnt vmcnt(0)" ::: "memory");
                #pragma unroll
                for (int it = 0; it < 8; it++)
                    *(float4*)(dh + it * 256) = v[it];
                #pragma unroll
                for (int it = 0; it < 8; it++)
                    *(float4*)(dl + it * 256) = v[8 + it];
            }
            __syncthreads();
            // ---- MFMA over own k-quarter: 8 k-steps x 3 split products ----
            f32x4 acc0 = {0.f, 0.f, 0.f, 0.f};
            f32x4 acc1 = {0.f, 0.f, 0.f, 0.f};
            #pragma unroll
            for (int ks = 0; ks < 8; ks++) {
                bf16x8 ah = *(const bf16x8*)(ah_base + ks * 64);
                bf16x8 al = *(const bf16x8*)(al_base + ks * 64);
                if (ks & 1) {
                    acc1 = __builtin_amdgcn_mfma_f32_16x16x32_bf16(ah, wh[ks], acc1, 0, 0, 0);
                    acc1 = __builtin_amdgcn_mfma_f32_16x16x32_bf16(al, wh[ks], acc1, 0, 0, 0);
                    acc1 = __builtin_amdgcn_mfma_f32_16x16x32_bf16(ah, wl[ks], acc1, 0, 0, 0);
                } else {
                    acc0 = __builtin_amdgcn_mfma_f32_16x16x32_bf16(ah, wh[ks], acc0, 0, 0, 0);
                    acc0 = __builtin_amdgcn_mfma_f32_16x16x32_bf16(al, wh[ks], acc0, 0, 0, 0);
                    acc0 = __builtin_amdgcn_mfma_f32_16x16x32_bf16(ah, wl[ks], acc0, 0, 0, 0);
                }
            }
            // ---- cross-wave k reduction -----------------------------------
            #pragma unroll
            for (int r = 0; r < 4; r++)
                redp[w * 256 + (kq * 4 + r) * 16 + row] = acc0[r] + acc1[r];
            __syncthreads();
            sum = redp[tid] + redp[256 + tid] + redp[512 + tid] + redp[768 + tid];
        }
        float pre = sum + xw;
        float hn = a_reg * hp + om * tanhf(pre);
        *xwp = hn;                    // plain store: output only, block-local
        if (t == SEQ - 1)
            out[(size_t)BATCH * SEQ * HID + (size_t)bglob * HID + jglob] = hn;
        // producer-side split of OWN value; sc1 stores into slot (t & 1)
        {
            unsigned short hi16, lo16;
            splitf(hn, &hi16, &lo16);
            unsigned hv = hi16, lv = lo16;
            char* ph = ph_base + (size_t)(t & 1) * HB_SLOT;
            char* pl = ph + HB_PLANE;
            asm volatile("global_store_short %0, %1, off sc0 sc1"
                         :: "v"(ph), "v"(hv) : "memory");
            asm volatile("global_store_short %0, %1, off sc0 sc1"
                         :: "v"(pl), "v"(lv) : "memory");
        }
        asm volatile("s_waitcnt vmcnt(0)" ::: "memory");  // drain all stores
        __syncthreads();              // ALL threads' stores drained
        if (tid == 0)
            __hip_atomic_fetch_add(cnt + (size_t)(t * 4 + bs) * CNT_STRIDE, 1,
                    __ATOMIC_RELAXED, __HIP_MEMORY_SCOPE_AGENT);
        hp = hn;
        xwp += HID;
    }
}

extern "C" void kernel_launch(void* const* d_in, const int* in_sizes, int n_in,
                              void* d_out, int out_size, void* d_ws, size_t ws_size,
                              hipStream_t stream) {
    const float* x          = (const float*)d_in[0];
    const float* complexity = (const float*)d_in[1];
    const float* Wrec       = (const float*)d_in[2];
    const float* Win        = (const float*)d_in[3];
    const float* bias       = (const float*)d_in[4];
    const float* tau_bands  = (const float*)d_in[5];
    const float* mixer_w    = (const float*)d_in[6];
    const float* mixer_b    = (const float*)d_in[7];
    float* out = (float*)d_out;

    // workspace layout: alpha | counters | Win hi | Win lo | hbuf
    float* alpha = (float*)d_ws;                                    // 256 B
    int*   cnt   = (int*)((char*)d_ws + 256);                       // 262144 B
    unsigned short* whi  = (unsigned short*)((char*)d_ws + 266240); // 2 MB
    unsigned short* wlo  = (unsigned short*)((char*)d_ws + 266240 + 2097152);
    unsigned short* hbuf = (unsigned short*)((char*)d_ws + 266240 + 4194304);

    hipMemsetAsync(cnt, 0, SEQ * 4 * CNT_STRIDE * sizeof(int), stream);
    alpha_kernel<<<1, 64, 0, stream>>>(complexity, tau_bands, mixer_w, mixer_b, alpha);
    win_split<<<1024, 256, 0, stream>>>(Win, whi, wlo);

    hipFuncSetAttribute((const void*)in_gemm_mfma,
                        hipFuncAttributeMaxDynamicSharedMemorySize, IG_LDS);
    in_gemm_mfma<<<dim3(512, 16), 256, IG_LDS, stream>>>(x, whi, wlo, bias, out);

    hipFuncSetAttribute((const void*)recur_coop,
                        hipFuncAttributeMaxDynamicSharedMemorySize, LDS_TOTAL);
    void* args[] = { (void*)&Wrec, (void*)&alpha, (void*)&out, (void*)&cnt, (void*)&hbuf };
    hipLaunchCooperativeKernel((void*)recur_coop, dim3(256), dim3(256),
                               args, LDS_TOTAL, stream);
}

// Round 13
// 2460.001 us; speedup vs baseline: 1.3838x; 1.0342x over previous
//
#include <hip/hip_runtime.h>
#include <math.h>

#define BATCH 64
#define SEQ 512
#define DIM 1024
#define HID 1024
#define KBANDS 4
#define DT_C 0.05f
#define CNT_STRIDE 32   // one counter per 128B line

typedef short bf16x8 __attribute__((ext_vector_type(8)));
typedef float f32x4 __attribute__((ext_vector_type(4)));

__device__ __forceinline__ unsigned bf16rn(float x) {
    unsigned u = __float_as_uint(x);
    return (u + 0x7fffu + ((u >> 16) & 1u)) >> 16;
}

__device__ __forceinline__ void splitf(float f, unsigned short* hi, unsigned short* lo) {
    unsigned h = bf16rn(f);
    float r = f - __uint_as_float(h << 16);
    *hi = (unsigned short)h;
    *lo = (unsigned short)bf16rn(r);
}

__device__ __forceinline__ void split_bf16(float4 f, ushort4* hi, ushort4* lo) {
    unsigned short h0, h1, h2, h3, l0, l1, l2, l3;
    splitf(f.x, &h0, &l0); splitf(f.y, &h1, &l1);
    splitf(f.z, &h2, &l2); splitf(f.w, &h3, &l3);
    *hi = make_ushort4(h0, h1, h2, h3);
    *lo = make_ushort4(l0, l1, l2, l3);
}

// ---------------- alpha: softmax tau mixer -> alpha[b] ----------------
__global__ void alpha_kernel(const float* __restrict__ complexity,
                             const float* __restrict__ tau_bands,
                             const float* __restrict__ mixer_w,
                             const float* __restrict__ mixer_b,
                             float* __restrict__ alpha) {
    int b = threadIdx.x;
    if (b < BATCH) {
        float c = complexity[b];
        float lg[KBANDS];
        float mx = -1e30f;
        #pragma unroll
        for (int k = 0; k < KBANDS; k++) {
            lg[k] = c * mixer_w[k] + mixer_b[k];
            mx = fmaxf(mx, lg[k]);
        }
        float se = 0.f, tau = 0.f;
        #pragma unroll
        for (int k = 0; k < KBANDS; k++) {
            float e = expf(lg[k] - mx);
            se += e;
            tau += tau_bands[k] * e;
        }
        tau /= se;
        alpha[b] = expf(-DT_C / tau);
    }
}

// ---------------- W_in -> bf16 hi/lo planes (once) --------------------
__global__ __launch_bounds__(256) void win_split(const float* __restrict__ win,
                                                 unsigned short* __restrict__ whi,
                                                 unsigned short* __restrict__ wlo) {
    size_t i = ((size_t)blockIdx.x * 256 + threadIdx.x) * 4;
    float4 f = *(const float4*)(win + i);
    ushort4 h4, l4;
    split_bf16(f, &h4, &l4);
    *(ushort4*)(whi + i) = h4;
    *(ushort4*)(wlo + i) = l4;
}

// ------------- xw = x @ W_in^T + bias via bf16x3 MFMA (M-owner grid) --------
// 512 blocks x 512 threads (8 waves). Block owns 64 M rows ACROSS ALL N=1024:
// each x element loaded+split EXACTLY ONCE (R12's 16x redundant split was the
// ~800us cost). A split on the fly into LDS; B (preconverted whi/wlo planes,
// 4MB, L2-resident) loaded DIRECTLY global->frag regs (no B LDS).
// Wave w owns n-range [128w, 128w+128): acc[4 mt][8 nt] f32x4 = 128 VGPRs.
// Fragment/D mappings identical to R12's passing kernel.
#define RP 272                       // bytes per LDS row (128 bf16 + 8 pad)
#define IG_LDS (2 * 64 * RP)         // Ahi + Alo = 34816 B

__global__ __launch_bounds__(512) void in_gemm_mfma(const float* __restrict__ x,
                                                    const unsigned short* __restrict__ whi,
                                                    const unsigned short* __restrict__ wlo,
                                                    const float* __restrict__ bias,
                                                    float* __restrict__ out) {
    extern __shared__ char lg[];
    char* Ahi = lg;
    char* Alo = lg + 64 * RP;

    int tid  = threadIdx.x;
    int m0   = blockIdx.x * 64;
    int lane = tid & 63;
    int w    = tid >> 6;             // wave 0..7: n-range [128w, 128w+128)
    int row  = lane & 15;
    int kq   = lane >> 4;

    // staging map: thread covers (srow = tid>>3, 16 floats at (tid&7)*16)
    int srow = tid >> 3;             // 0..63
    int skeg = (tid & 7) * 16;       // 0..112
    const float* xsrc = x + (size_t)(m0 + srow) * 1024 + skeg;
    char* dah = Ahi + srow * RP + skeg * 2;
    char* dal = Alo + srow * RP + skeg * 2;

    f32x4 acc[4][8];
    #pragma unroll
    for (int mt = 0; mt < 4; mt++)
        #pragma unroll
        for (int nt = 0; nt < 8; nt++)
            acc[mt][nt] = (f32x4){0.f, 0.f, 0.f, 0.f};

    for (int k0 = 0; k0 < 1024; k0 += 128) {
        // ---- stage A: load x once, split fp32 -> bf16 hi/lo in LDS --------
        #pragma unroll
        for (int i = 0; i < 4; i++) {
            float4 f = *(const float4*)(xsrc + k0 + i * 4);
            ushort4 h4, l4;
            split_bf16(f, &h4, &l4);
            *(ushort4*)(dah + i * 8) = h4;
            *(ushort4*)(dal + i * 8) = l4;
        }
        __syncthreads();
        // ---- MFMA: 4 ks x 8 nt x 4 mt x 3 split products ------------------
        #pragma unroll
        for (int ks = 0; ks < 4; ks++) {
            int koff = (ks * 32 + kq * 8) * 2;
            bf16x8 ah[4], al[4];
            #pragma unroll
            for (int mt = 0; mt < 4; mt++) {
                ah[mt] = *(const bf16x8*)(Ahi + (mt * 16 + row) * RP + koff);
                al[mt] = *(const bf16x8*)(Alo + (mt * 16 + row) * RP + koff);
            }
            #pragma unroll
            for (int nt = 0; nt < 8; nt++) {
                size_t boff = (size_t)(w * 128 + nt * 16 + row) * 1024
                            + k0 + ks * 32 + kq * 8;
                bf16x8 bh = *(const bf16x8*)(whi + boff);
                bf16x8 bl = *(const bf16x8*)(wlo + boff);
                #pragma unroll
                for (int mt = 0; mt < 4; mt++) {
                    acc[mt][nt] = __builtin_amdgcn_mfma_f32_16x16x32_bf16(ah[mt], bh, acc[mt][nt], 0, 0, 0);
                    acc[mt][nt] = __builtin_amdgcn_mfma_f32_16x16x32_bf16(al[mt], bh, acc[mt][nt], 0, 0, 0);
                    acc[mt][nt] = __builtin_amdgcn_mfma_f32_16x16x32_bf16(ah[mt], bl, acc[mt][nt], 0, 0, 0);
                }
            }
        }
        __syncthreads();
    }
    // ---- epilogue: D(m = mt*16 + kq*4 + r, n = 128w + nt*16 + row) + bias --
    #pragma unroll
    for (int nt = 0; nt < 8; nt++) {
        int n = w * 128 + nt * 16 + row;
        float bn = bias[n];
        #pragma unroll
        for (int mt = 0; mt < 4; mt++)
            #pragma unroll
            for (int r = 0; r < 4; r++)
                out[(size_t)(m0 + mt * 16 + kq * 4 + r) * 1024 + n] = acc[mt][nt][r] + bn;
    }
}

// ------------- cooperative recurrence (EXACT R5/R12, proven 1.74-1.87ms) ----
// 256 blocks = 4 b-slices x 64 j-slices; 4 waves/block.
// bf16 hi/lo PARITY planes in hbuf; producer splits own value, 2 sc1 short
// stores; consumer sc1 dwordx4 staging -> plain-pitch LDS -> bf16x8 frags ->
// 24 MFMA; W frags register-resident. Sync: per-(t,bs) 128B-strided counters;
// tid0 relaxed poll <64 -> syncthreads; epilogue: stores -> vmcnt(0) ->
// syncthreads -> tid0 fetch_add(+1).
// R7 (flag-store sync), R10 (deep cacheable buffer), R11 (per-group gate)
// all measured WORSE -- do not revisit.

#define HPITCH 2064               // bytes per LDS plane row (1024*2 + 16 pad)
#define LDS_HI  0
#define LDS_LO  33024             // 16*HPITCH
#define LDS_RED 66048             // 4KB reduction buffer
#define LDS_TOTAL 70144
#define HB_PLANE 131072           // bytes per hi (or lo) plane [64][1024] ushort
#define HB_SLOT  262144           // hi+lo planes per parity slot

__global__ __launch_bounds__(256, 1) void recur_coop(const float* __restrict__ Wrec,
                                                     const float* __restrict__ alpha,
                                                     float* __restrict__ out,
                                                     int* __restrict__ cnt,
                                                     unsigned short* __restrict__ hbuf) {
    extern __shared__ char lbase[];

    int tid  = threadIdx.x;
    int bs   = blockIdx.x & 3;        // b-slice 0..3
    int js   = blockIdx.x >> 2;       // j-slice 0..63
    int lane = tid & 63;
    int w    = tid >> 6;              // wave 0..3 = k-quarter owner
    int row  = lane & 15;             // frag row: batch (A) / j (B)
    int kq   = lane >> 4;             // k-subchunk within 32-wide MFMA window

    // ---- W fragments (B operand), converted ONCE into registers ----------
    bf16x8 wh[8], wl[8];
    {
        const float* wsrc = Wrec + (size_t)(js * 16 + row) * HID + w * 256 + kq * 8;
        #pragma unroll
        for (int ks = 0; ks < 8; ks++) {
            float4 f0 = *(const float4*)(wsrc + ks * 32);
            float4 f1 = *(const float4*)(wsrc + ks * 32 + 4);
            union { unsigned short u[8]; bf16x8 v; } H, L;
            splitf(f0.x, &H.u[0], &L.u[0]);
            splitf(f0.y, &H.u[1], &L.u[1]);
            splitf(f0.z, &H.u[2], &L.u[2]);
            splitf(f0.w, &H.u[3], &L.u[3]);
            splitf(f1.x, &H.u[4], &L.u[4]);
            splitf(f1.y, &H.u[5], &L.u[5]);
            splitf(f1.z, &H.u[6], &L.u[6]);
            splitf(f1.w, &H.u[7], &L.u[7]);
            wh[ks] = H.v;
            wl[ks] = L.v;
        }
    }

    // epilogue mapping: thread owns (batch bs*16 + eb, hidden j js*16 + ej)
    int eb = tid >> 4;
    int ej = tid & 15;
    int bglob = bs * 16 + eb;
    int jglob = js * 16 + ej;
    float a_reg = alpha[bglob];
    float om = 1.f - a_reg;
    float* xwp = out + (size_t)bglob * SEQ * HID + jglob;

    // staging mapping (R5): srow = batch row 0..15, sl16 = k-chunk lane
    int srow = tid >> 4, sl16 = tid & 15;
    const char* hb_lane = (const char*)hbuf + (size_t)(bs * 16 + srow) * 2048 + sl16 * 16;
    char* ph_base = (char*)hbuf + (size_t)bglob * 2048 + jglob * 2;

    float hp = 0.f;
    float* redp = (float*)(lbase + LDS_RED);
    const char* ah_base = lbase + LDS_HI + row * HPITCH + (w * 256 + kq * 8) * 2;
    const char* al_base = lbase + LDS_LO + row * HPITCH + (w * 256 + kq * 8) * 2;
    char* dh = lbase + LDS_HI + srow * HPITCH + sl16 * 16;
    char* dl = lbase + LDS_LO + srow * HPITCH + sl16 * 16;

    for (int t = 0; t < SEQ; t++) {
        float xw = *xwp;              // independent of h[t-1]; issue early
        float sum = 0.f;
        if (t > 0) {
            if (tid == 0) {
                int* cp = cnt + (size_t)((t - 1) * 4 + bs) * CNT_STRIDE;
                int spins = 0;
                while (__hip_atomic_load(cp, __ATOMIC_RELAXED,
                                         __HIP_MEMORY_SCOPE_AGENT) < 64) {
                    __builtin_amdgcn_s_sleep(1);
                    if (++spins >= 8192) {      // insurance re-check via RMW
                        spins = 0;
                        if (__hip_atomic_fetch_add(cp, 0, __ATOMIC_RELAXED,
                                __HIP_MEMORY_SCOPE_AGENT) >= 64) break;
                    }
                }
            }
            __syncthreads();          // broadcast: h[t-1] slot globally visible
            // ---- stage bf16 hi/lo planes of h[t-1] (sc1 loads) ------------
            {
                const char* bh = hb_lane + (size_t)((t - 1) & 1) * HB_SLOT;
                const char* bl = bh + HB_PLANE;
                float4 v[16];
                #pragma unroll
                for (int it = 0; it < 8; it++)
                    asm volatile("global_load_dwordx4 %0, %1, off offset:%2 sc0 sc1"
                                 : "=v"(v[it]) : "v"(bh), "i"(it * 256) : "memory");
                #pragma unroll
                for (int it = 0; it < 8; it++)
                    asm volatile("global_load_dwordx4 %0, %1, off offset:%2 sc0 sc1"
                                 : "=v"(v[8 + it]) : "v"(bl), "i"(it * 256) : "memory");
                asm volatile("s_waitcnt vmcnt(0)" ::: "memory");
                #pragma unroll
                for (int it = 0; it < 8; it++)
                    *(float4*)(dh + it * 256) = v[it];
                #pragma unroll
                for (int it = 0; it < 8; it++)
                    *(float4*)(dl + it * 256) = v[8 + it];
            }
            __syncthreads();
            // ---- MFMA over own k-quarter: 8 k-steps x 3 split products ----
            f32x4 acc0 = {0.f, 0.f, 0.f, 0.f};
            f32x4 acc1 = {0.f, 0.f, 0.f, 0.f};
            #pragma unroll
            for (int ks = 0; ks < 8; ks++) {
                bf16x8 ah = *(const bf16x8*)(ah_base + ks * 64);
                bf16x8 al = *(const bf16x8*)(al_base + ks * 64);
                if (ks & 1) {
                    acc1 = __builtin_amdgcn_mfma_f32_16x16x32_bf16(ah, wh[ks], acc1, 0, 0, 0);
                    acc1 = __builtin_amdgcn_mfma_f32_16x16x32_bf16(al, wh[ks], acc1, 0, 0, 0);
                    acc1 = __builtin_amdgcn_mfma_f32_16x16x32_bf16(ah, wl[ks], acc1, 0, 0, 0);
                } else {
                    acc0 = __builtin_amdgcn_mfma_f32_16x16x32_bf16(ah, wh[ks], acc0, 0, 0, 0);
                    acc0 = __builtin_amdgcn_mfma_f32_16x16x32_bf16(al, wh[ks], acc0, 0, 0, 0);
                    acc0 = __builtin_amdgcn_mfma_f32_16x16x32_bf16(ah, wl[ks], acc0, 0, 0, 0);
                }
            }
            // ---- cross-wave k reduction -----------------------------------
            #pragma unroll
            for (int r = 0; r < 4; r++)
                redp[w * 256 + (kq * 4 + r) * 16 + row] = acc0[r] + acc1[r];
            __syncthreads();
            sum = redp[tid] + redp[256 + tid] + redp[512 + tid] + redp[768 + tid];
        }
        float pre = sum + xw;
        float hn = a_reg * hp + om * tanhf(pre);
        *xwp = hn;                    // plain store: output only, block-local
        if (t == SEQ - 1)
            out[(size_t)BATCH * SEQ * HID + (size_t)bglob * HID + jglob] = hn;
        // producer-side split of OWN value; sc1 stores into slot (t & 1)
        {
            unsigned short hi16, lo16;
            splitf(hn, &hi16, &lo16);
            unsigned hv = hi16, lv = lo16;
            char* ph = ph_base + (size_t)(t & 1) * HB_SLOT;
            char* pl = ph + HB_PLANE;
            asm volatile("global_store_short %0, %1, off sc0 sc1"
                         :: "v"(ph), "v"(hv) : "memory");
            asm volatile("global_store_short %0, %1, off sc0 sc1"
                         :: "v"(pl), "v"(lv) : "memory");
        }
        asm volatile("s_waitcnt vmcnt(0)" ::: "memory");  // drain all stores
        __syncthreads();              // ALL threads' stores drained
        if (tid == 0)
            __hip_atomic_fetch_add(cnt + (size_t)(t * 4 + bs) * CNT_STRIDE, 1,
                    __ATOMIC_RELAXED, __HIP_MEMORY_SCOPE_AGENT);
        hp = hn;
        xwp += HID;
    }
}

extern "C" void kernel_launch(void* const* d_in, const int* in_sizes, int n_in,
                              void* d_out, int out_size, void* d_ws, size_t ws_size,
                              hipStream_t stream) {
    const float* x          = (const float*)d_in[0];
    const float* complexity = (const float*)d_in[1];
    const float* Wrec       = (const float*)d_in[2];
    const float* Win        = (const float*)d_in[3];
    const float* bias       = (const float*)d_in[4];
    const float* tau_bands  = (const float*)d_in[5];
    const float* mixer_w    = (const float*)d_in[6];
    const float* mixer_b    = (const float*)d_in[7];
    float* out = (float*)d_out;

    // workspace layout (identical to R12): alpha | counters | Win hi | Win lo | hbuf
    float* alpha = (float*)d_ws;                                    // 256 B
    int*   cnt   = (int*)((char*)d_ws + 256);                       // 262144 B
    unsigned short* whi  = (unsigned short*)((char*)d_ws + 266240); // 2 MB
    unsigned short* wlo  = (unsigned short*)((char*)d_ws + 266240 + 2097152);
    unsigned short* hbuf = (unsigned short*)((char*)d_ws + 266240 + 4194304);

    hipMemsetAsync(cnt, 0, SEQ * 4 * CNT_STRIDE * sizeof(int), stream);
    alpha_kernel<<<1, 64, 0, stream>>>(complexity, tau_bands, mixer_w, mixer_b, alpha);
    win_split<<<1024, 256, 0, stream>>>(Win, whi, wlo);

    hipFuncSetAttribute((const void*)in_gemm_mfma,
                        hipFuncAttributeMaxDynamicSharedMemorySize, IG_LDS);
    in_gemm_mfma<<<dim3(512), 512, IG_LDS, stream>>>(x, whi, wlo, bias, out);

    hipFuncSetAttribute((const void*)recur_coop,
                        hipFuncAttributeMaxDynamicSharedMemorySize, LDS_TOTAL);
    void* args[] = { (void*)&Wrec, (void*)&alpha, (void*)&out, (void*)&cnt, (void*)&hbuf };
    hipLaunchCooperativeKernel((void*)recur_coop, dim3(256), dim3(256),
                               args, LDS_TOTAL, stream);
}